// Round 6
// baseline (1010.709 us; speedup 1.0000x reference)
//
#include <hip/hip_runtime.h>
#include <hip/hip_bf16.h>
#include <math.h>

#define BN 4
#define CHN 64
#define HH 256
#define WW 256
#define HWSZ (HH*WW)
#define EPSV 1e-5f
#define CP 72   // LDS px-row stride in shorts (144 B): 16B-aligned, 0 conflicts (r4-measured)

typedef __attribute__((ext_vector_type(8)))  short  short8;
typedef __attribute__((ext_vector_type(4)))  short  short4v;
typedef __attribute__((ext_vector_type(16))) float  floatx16;

__device__ __forceinline__ int refl(int i, int n){ if(i<0)i=-i; if(i>=n)i=2*n-2-i; return i; }
__device__ __forceinline__ short f2bf(float f){ __hip_bfloat16 h=__float2bfloat16(f); return __builtin_bit_cast(short,h); }
__device__ __forceinline__ float bf2f(short s){ unsigned u=((unsigned)(unsigned short)s)<<16; return __builtin_bit_cast(float,u); }

// ---------------- guide: K[b,t,y,x] = exp(-0.5*(g_shift - g)^2), fp32 ----------------
__global__ void guide_kernel(const float* __restrict__ x, float* __restrict__ Kb) {
    int idx = blockIdx.x * 256 + threadIdx.x;
    if (idx >= BN*HWSZ) return;
    int b = idx / HWSZ, p = idx - b*HWSZ;
    int y = p / WW, xx = p - y*WW;
    const float* g = x + b*HWSZ;
    float gc = g[p];
#pragma unroll
    for (int t = 0; t < 9; ++t) {
        int yy  = refl(y + t/3 - 1, HH);
        int xx2 = refl(xx + t%3 - 1, WW);
        float d = g[yy*WW + xx2] - gc;
        Kb[(b*9 + t)*HWSZ + p] = __expf(-0.5f*d*d);
    }
}

// ---------------- pack all 7 weight tensors into 32x32x16 A-fragment order ----------------
// frag = (t*4+cg)*2+oh ; o = oh*32+(lane&31) ; c = cg*16+(lane>>5)*8+j
__global__ void pack_all(const float* w1,const float* w2,const float* w3,const float* w4,
                         const float* w5,const float* w6,const float* w7, short* __restrict__ Ap){
    const float* wsrc[7] = {w1,w2,w3,w4,w5,w6,w7};
    int layer = blockIdx.y;
    int tid = blockIdx.x*256 + threadIdx.x;          // 0..36863
    int j    = tid & 7;
    int lane = (tid >> 3) & 63;
    int frag = tid >> 9;                             // 0..71
    int oh = frag & 1, cg = (frag >> 1) & 3, t = frag >> 3;
    int o = oh*32 + (lane & 31);
    int c = cg*16 + (lane >> 5)*8 + j;
    Ap[(size_t)layer*36864 + tid] = f2bf(wsrc[layer][(o*CHN + c)*9 + t]);
}

// ---------------- conv1x1 -> A, channels-last bf16 [b][y][x][c] ----------------
__global__ void conv1x1_kernel(const float* __restrict__ x, const float* __restrict__ w0,
                               const float* __restrict__ b0, short* __restrict__ A){
    int idx = blockIdx.x*256 + threadIdx.x;          // BN*HWSZ*8 (px-octets)
    int oc = idx & 7;
    int px = (idx >> 3) % HWSZ;
    int b  = idx / (HWSZ*8);
    float xv = x[(size_t)b*HWSZ + px];
    short8 r;
#pragma unroll
    for (int j = 0; j < 8; ++j) {
        int c = oc*8 + j;
        r[j] = f2bf(fmaf(w0[c], xv, b0[c]));
    }
    *(short8*)(A + ((size_t)(b*HWSZ + px))*64 + oc*8) = r;
}

// ---------------- zero the stats accumulators (6 layers x [4][64][2]) ----------------
__global__ void zero_stats(float* st){
    int idx = blockIdx.x*256 + threadIdx.x;
    if (idx < 6*BN*64*2) st[idx] = 0.f;
}

// ---------------- PAC conv, implicit GEMM on mfma_32x32x16_bf16 (r4 structure) ----------------
// Block: 64 o x (32 px x 2 rows); waves (oh = w&1, wrow = w>>1): 32 o x 32 px.
// h halo (4 rows x 34 px x 64 c, bf16 channels-last) staged ONCE; taps read shifted windows.
// K applied per tap on the C-tile (col=lane&31 = pixel): acc += K[t,px]*(W_t x h).
// NORM=1: staging applies (v-mean)*rstd,relu (fuses applyrelu).
// STAT=1: epilogue shuffle-reduces sum/sumsq of the bf16-rounded outputs and atomicAdds
//         per-(b,c) partials (replaces the separate stats_k dispatch).
template<int NORM, int HASK, int FINAL, int STAT>
__global__ void __launch_bounds__(256, 3) pac_mfma(
    const short* __restrict__ hin, const float* __restrict__ Kb,
    const short* __restrict__ Ap, const float* __restrict__ bias,
    const float* __restrict__ stin, short* __restrict__ outb, float* __restrict__ outf,
    float* __restrict__ stout)
{
    __shared__ short lds[4*34*CP];                   // 19584 B
    __shared__ float sred[4][2][16][2];              // [wave][hi][reg][stat], 1 KB

    int b  = blockIdx.z;
    int y0 = blockIdx.y * 2;
    int x0 = blockIdx.x * 32;
    int tid = threadIdx.x, lane = tid & 63, wave = tid >> 6;
    int ln2 = lane & 31, hi = lane >> 5, oh = wave & 1, wrow = wave >> 1;
    const short* hb = hin + (size_t)b*HWSZ*64;
    const float* stb = stin + b*64*2;

    // ---- kv loads FIRST: 9 independent global loads overlap staging latency ----
    float kv[9];
    if (HASK) {
#pragma unroll
        for (int t = 0; t < 9; ++t)
            kv[t] = Kb[((size_t)(b*9 + t))*HWSZ + (y0 + wrow)*WW + x0 + ln2];
    }

    // ---- stage 4 rows x 32 px x 64 c (pow2 chunking, coalesced 16B) ----
    float mean[8], rstd[8];
    if (NORM) {
        int c0 = (tid & 7) * 8;                      // thread's c-octet fixed (256%8==0)
#pragma unroll
        for (int j = 0; j < 8; ++j) {
            float s = stb[(c0+j)*2], s2 = stb[(c0+j)*2+1];
            float m = s * (1.f/HWSZ);
            float var = s2 * (1.f/HWSZ) - m*m;
            mean[j] = m; rstd[j] = rsqrtf(fmaxf(var, 0.f) + EPSV);
        }
    }
#pragma unroll
    for (int it = 0; it < 4; ++it) {
        int chunk = tid + it*256;                    // 1024 chunks
        int r = chunk >> 8, o = chunk & 255, px = o >> 3, oc = o & 7;
        int yy = refl(y0 - 1 + r, HH);
        short8 v = *(const short8*)(hb + ((size_t)(yy*WW + x0 + px))*64 + oc*8);
        if (NORM) {
#pragma unroll
            for (int j = 0; j < 8; ++j) {
                float f = bf2f(v[j]);
                f = fmaxf((f - mean[j]) * rstd[j], 0.f);
                v[j] = f2bf(f);
            }
        }
        *(short8*)(lds + (r*34 + 1 + px)*CP + oc*8) = v;
    }
    // ---- halo columns x0-1 and x0+32 (x-reflected at edges) ----
    {
        int r = tid >> 6, c = tid & 63;
        int xm = (x0 == 0) ? 1 : x0 - 1;
        int xp = (x0 + 32 == WW) ? WW - 2 : x0 + 32;
        int yy = refl(y0 - 1 + r, HH);
        float fa = bf2f(hb[((size_t)(yy*WW + xm))*64 + c]);
        float fb = bf2f(hb[((size_t)(yy*WW + xp))*64 + c]);
        if (NORM) {
            float s = stb[c*2], s2 = stb[c*2+1];
            float m = s * (1.f/HWSZ);
            float rs = rsqrtf(fmaxf(s2*(1.f/HWSZ) - m*m, 0.f) + EPSV);
            fa = fmaxf((fa - m)*rs, 0.f);
            fb = fmaxf((fb - m)*rs, 0.f);
        }
        lds[(r*34 + 0)*CP + c]  = f2bf(fa);
        lds[(r*34 + 33)*CP + c] = f2bf(fb);
    }
    __syncthreads();

    floatx16 acc = (floatx16)(0.f);
    const short8* Ap8 = (const short8*)Ap;
#pragma unroll
    for (int t = 0; t < 9; ++t) {
        int dy = t/3 - 1, dx = t%3 - 1;
        int rr = wrow + dy + 1;                      // 0..3
        // batch all loads for this tap, then 4 back-to-back MFMAs (load-ahead)
        short8 bfr[4], af[4];
#pragma unroll
        for (int cg = 0; cg < 4; ++cg) {
            bfr[cg] = *(const short8*)(lds + (rr*34 + 1 + ln2 + dx)*CP + cg*16 + hi*8);
            af[cg]  = Ap8[((size_t)(t*4 + cg)*2 + oh)*64 + lane];
        }
        if (HASK) {
            floatx16 tmp = (floatx16)(0.f);
#pragma unroll
            for (int cg = 0; cg < 4; ++cg)
                tmp = __builtin_amdgcn_mfma_f32_32x32x16_bf16(af[cg], bfr[cg], tmp, 0, 0, 0);
#pragma unroll
            for (int r = 0; r < 16; ++r) acc[r] = fmaf(kv[t], tmp[r], acc[r]);
        } else {
#pragma unroll
            for (int cg = 0; cg < 4; ++cg)
                acc = __builtin_amdgcn_mfma_f32_32x32x16_bf16(af[cg], bfr[cg], acc, 0, 0, 0);
        }
    }

    // ---- epilogue: C/D col=lane&31 (px), row o = (reg&3)+8*(reg>>2)+4*hi+32*oh ----
    int y = y0 + wrow, x = x0 + ln2;
    float sv[16];                                    // bf16-rounded stored values (for stats)
#pragma unroll
    for (int q = 0; q < 4; ++q) {
        int o0 = oh*32 + hi*4 + 8*q;                 // regs 4q..4q+3 -> o0..o0+3
        float4 bq = *(const float4*)(bias + o0);
        if (FINAL) {
#pragma unroll
            for (int jj = 0; jj < 4; ++jj) {
                float val = acc[q*4 + jj] + ((float*)&bq)[jj];
                val = fmaxf(val, 0.f);
                outf[((size_t)(b*64 + o0 + jj))*HWSZ + y*WW + x] = val;  // NCHW fp32
            }
        } else {
            short4v pk;
#pragma unroll
            for (int jj = 0; jj < 4; ++jj) {
                pk[jj] = f2bf(acc[q*4 + jj] + ((float*)&bq)[jj]);
                sv[q*4 + jj] = bf2f(pk[jj]);
            }
            *(short4v*)(outb + ((size_t)b*HWSZ + (size_t)(y*WW + x))*64 + o0) = pk;
        }
    }

    if (STAT) {
        // reduce over the 32 pixels (ln2) of this wave; hi-halves stay separate
        float s1[16], s2[16];
#pragma unroll
        for (int r = 0; r < 16; ++r) { s1[r] = sv[r]; s2[r] = sv[r]*sv[r]; }
#pragma unroll
        for (int mask = 1; mask < 32; mask <<= 1) {
#pragma unroll
            for (int r = 0; r < 16; ++r) {
                s1[r] += __shfl_xor(s1[r], mask);
                s2[r] += __shfl_xor(s2[r], mask);
            }
        }
        if (ln2 == 0) {
#pragma unroll
            for (int r = 0; r < 16; ++r) {
                sred[wave][hi][r][0] = s1[r];
                sred[wave][hi][r][1] = s2[r];
            }
        }
        __syncthreads();
        if (tid < 128) {
            int reg = tid & 15, hh = (tid >> 4) & 1, ohh = (tid >> 5) & 1, stat = tid >> 6;
            // waves with this oh: wave = ohh and ohh+2 (wrow 0/1)
            float v = sred[ohh][hh][reg][stat] + sred[ohh + 2][hh][reg][stat];
            int q = reg >> 2, jj = reg & 3;
            int c = ohh*32 + hh*4 + 8*q + jj;
            atomicAdd(&stout[(b*64 + c)*2 + stat], v);
        }
    }
}

// ---------------- A <- relu(A + (C-mean)*rstd), bf16 channels-last ----------------
__global__ void addnorm_relu(short* __restrict__ A, const short* __restrict__ C,
                             const float* __restrict__ st){
    int idx = blockIdx.x*256 + threadIdx.x;          // BN*HWSZ*8
    int oc = idx & 7;
    size_t pq = (size_t)(idx >> 3);
    int b = (int)(pq / HWSZ);
    size_t base = pq*64 + oc*8;
    short8 a = *(short8*)(A + base);
    short8 c = *(const short8*)(C + base);
#pragma unroll
    for (int j = 0; j < 8; ++j) {
        int cc = oc*8 + j;
        float s = st[(b*64+cc)*2], s2 = st[(b*64+cc)*2+1];
        float m = s * (1.f/HWSZ);
        float rs = rsqrtf(fmaxf(s2*(1.f/HWSZ) - m*m, 0.f) + EPSV);
        float f = bf2f(a[j]) + (bf2f(c[j]) - m)*rs;
        a[j] = f2bf(fmaxf(f, 0.f));
    }
    *(short8*)(A + base) = a;
}

extern "C" void kernel_launch(void* const* d_in, const int* in_sizes, int n_in,
                              void* d_out, int out_size, void* d_ws, size_t ws_size,
                              hipStream_t stream) {
    const float* x   = (const float*)d_in[0];
    // d_in[1] = grad_img: unused by the reference
    const float* w0  = (const float*)d_in[2];
    const float* b0  = (const float*)d_in[3];
    const float* wf  = (const float*)d_in[4];
    const float* bf  = (const float*)d_in[5];
    const float* w1a = (const float*)d_in[6];  const float* b1a = (const float*)d_in[7];
    const float* w1b = (const float*)d_in[8];  const float* b1b = (const float*)d_in[9];
    const float* w2a = (const float*)d_in[10]; const float* b2a = (const float*)d_in[11];
    const float* w2b = (const float*)d_in[12]; const float* b2b = (const float*)d_in[13];
    const float* w3a = (const float*)d_in[14]; const float* b3a = (const float*)d_in[15];
    const float* w3b = (const float*)d_in[16]; const float* b3b = (const float*)d_in[17];

    float* ws   = (float*)d_ws;
    float* Kb   = ws;                                 // 2,359,296 f (9.4 MB)
    short* A    = (short*)(Kb + (size_t)BN*9*HWSZ);   // 16,777,216 shorts (33.5 MB)
    short* Bb   = A + (size_t)BN*HWSZ*64;             // 16,777,216 shorts
    short* Apk  = Bb + (size_t)BN*HWSZ*64;            // 7*36864 shorts
    float* st   = (float*)(Apk + (size_t)7*36864 + 64); // 6 * 512 floats
    short* Cc   = (short*)d_out;                      // C scratch (bf16), then fp32 output

    zero_stats<<<12, 256, 0, stream>>>(st);
    pack_all<<<dim3(144, 7), 256, 0, stream>>>(w1a, w1b, w2a, w2b, w3a, w3b, wf, Apk);
    guide_kernel<<<(BN*HWSZ + 255)/256, 256, 0, stream>>>(x, Kb);
    conv1x1_kernel<<<BN*HWSZ*8/256, 256, 0, stream>>>(x, w0, b0, A);

    dim3 g(WW/32, HH/2, BN);                          // 8 x 128 x 4 = 4096 blocks
    const int eblk = BN*HWSZ*8/256;
    const float* biasA[3] = {b1a, b2a, b3a};
    const float* biasB[3] = {b1b, b2b, b3b};

    for (int rb = 0; rb < 3; ++rb) {
        float* stB = st + (size_t)(2*rb)   * BN*64*2;
        float* stC = st + (size_t)(2*rb+1) * BN*64*2;
        // pac_a: raw staging, K-modulated, bf16 out, fused stats -> stB
        pac_mfma<0,1,0,1><<<g, 256, 0, stream>>>(A, Kb, Apk + (size_t)(2*rb)*36864, biasA[rb],
                                                 nullptr, Bb, nullptr, stB);
        // pac_b: staging applies norm(B)+relu, K-modulated, bf16 out, fused stats -> stC
        pac_mfma<1,1,0,1><<<g, 256, 0, stream>>>(Bb, Kb, Apk + (size_t)(2*rb+1)*36864, biasB[rb],
                                                 stB, Cc, nullptr, stC);
        addnorm_relu<<<eblk, 256, 0, stream>>>(A, Cc, stC);
    }

    // final: plain 3x3 conv (no K), bias+relu, fp32 NCHW to d_out
    pac_mfma<0,0,1,0><<<g, 256, 0, stream>>>(A, Kb, Apk + (size_t)6*36864, bf,
                                             nullptr, nullptr, (float*)d_out, nullptr);
}

// Round 7
// 609.153 us; speedup vs baseline: 1.6592x; 1.6592x over previous
//
#include <hip/hip_runtime.h>
#include <hip/hip_bf16.h>
#include <math.h>

#define BN 4
#define CHN 64
#define HH 256
#define WW 256
#define HWSZ (HH*WW)
#define EPSV 1e-5f
#define CP 72   // LDS px-row stride in shorts (144 B): 16B-aligned, 0 conflicts (r4-measured)

typedef __attribute__((ext_vector_type(8)))  short  short8;
typedef __attribute__((ext_vector_type(4)))  short  short4v;
typedef __attribute__((ext_vector_type(2)))  float  float2v;
typedef __attribute__((ext_vector_type(16))) float  floatx16;

__device__ __forceinline__ int refl(int i, int n){ if(i<0)i=-i; if(i>=n)i=2*n-2-i; return i; }
__device__ __forceinline__ short f2bf(float f){ __hip_bfloat16 h=__float2bfloat16(f); return __builtin_bit_cast(short,h); }
__device__ __forceinline__ float bf2f(short s){ unsigned u=((unsigned)(unsigned short)s)<<16; return __builtin_bit_cast(float,u); }

// ---------------- guide: K[b,t,y,x] = exp(-0.5*(g_shift - g)^2), fp32 ----------------
__global__ void guide_kernel(const float* __restrict__ x, float* __restrict__ Kb) {
    int idx = blockIdx.x * 256 + threadIdx.x;
    if (idx >= BN*HWSZ) return;
    int b = idx / HWSZ, p = idx - b*HWSZ;
    int y = p / WW, xx = p - y*WW;
    const float* g = x + b*HWSZ;
    float gc = g[p];
#pragma unroll
    for (int t = 0; t < 9; ++t) {
        int yy  = refl(y + t/3 - 1, HH);
        int xx2 = refl(xx + t%3 - 1, WW);
        float d = g[yy*WW + xx2] - gc;
        Kb[(b*9 + t)*HWSZ + p] = __expf(-0.5f*d*d);
    }
}

// ---------------- pack all 7 weight tensors into 32x32x16 A-fragment order ----------------
// frag = (t*4+cg)*2+oh ; o = oh*32+(lane&31) ; c = cg*16+(lane>>5)*8+j
__global__ void pack_all(const float* w1,const float* w2,const float* w3,const float* w4,
                         const float* w5,const float* w6,const float* w7, short* __restrict__ Ap){
    const float* wsrc[7] = {w1,w2,w3,w4,w5,w6,w7};
    int layer = blockIdx.y;
    int tid = blockIdx.x*256 + threadIdx.x;          // 0..36863
    int j    = tid & 7;
    int lane = (tid >> 3) & 63;
    int frag = tid >> 9;                             // 0..71
    int oh = frag & 1, cg = (frag >> 1) & 3, t = frag >> 3;
    int o = oh*32 + (lane & 31);
    int c = cg*16 + (lane >> 5)*8 + j;
    Ap[(size_t)layer*36864 + tid] = f2bf(wsrc[layer][(o*CHN + c)*9 + t]);
}

// ---------------- conv1x1 -> S0, channels-last bf16 [b][y][x][c] ----------------
__global__ void conv1x1_kernel(const float* __restrict__ x, const float* __restrict__ w0,
                               const float* __restrict__ b0, short* __restrict__ A){
    int idx = blockIdx.x*256 + threadIdx.x;          // BN*HWSZ*8 (px-octets)
    int oc = idx & 7;
    int px = (idx >> 3) % HWSZ;
    int b  = idx / (HWSZ*8);
    float xv = x[(size_t)b*HWSZ + px];
    short8 r;
#pragma unroll
    for (int j = 0; j < 8; ++j) {
        int c = oc*8 + j;
        r[j] = f2bf(fmaf(w0[c], xv, b0[c]));
    }
    *(short8*)(A + ((size_t)(b*HWSZ + px))*64 + oc*8) = r;
}

// ---------------- zero the stats accumulators (6 layers x [4][64][2]) ----------------
__global__ void zero_stats(float* st){
    int idx = blockIdx.x*256 + threadIdx.x;
    if (idx < 6*BN*64*2) st[idx] = 0.f;
}

// ---------------- PAC conv, implicit GEMM on mfma_32x32x16_bf16 ----------------
// r4 structure: block = 64 o x (32 px x 2 rows); waves (oh = w&1, wrow = w>>1).
// MODE 0: stage hin raw.  MODE 1: stage relu(norm(hin)) from stin.
// MODE 2 (fused addnorm): stage relu(hin + norm(cin)) from stin; designated-write
//         own pixels (bulk rows r=1,2) of the staged state to snew.
// Tap loop is software-pipelined: tap t+1's A-frags (global) and B-frags (LDS)
// load while tap t's MFMAs run; kv + tap0 A-frags issued before the barrier.
// K-apply: two independent tmp accumulators, packed float2 fma (v_pk_fma_f32).
template<int MODE, int HASK, int FINAL, int WRITES>
__global__ void __launch_bounds__(256, 2) pac_mfma(
    const short* __restrict__ hin, const short* __restrict__ cin,
    const float* __restrict__ Kb,
    const short* __restrict__ Ap, const float* __restrict__ bias,
    const float* __restrict__ stin, short* __restrict__ outb, float* __restrict__ outf,
    short* __restrict__ snew)
{
    __shared__ short lds[4*34*CP];                   // 19584 B

    int b  = blockIdx.z;
    int y0 = blockIdx.y * 2;
    int x0 = blockIdx.x * 32;
    int tid = threadIdx.x, lane = tid & 63, wave = tid >> 6;
    int ln2 = lane & 31, hi = lane >> 5, oh = wave & 1, wrow = wave >> 1;
    const short* hb = hin + (size_t)b*HWSZ*64;
    const short* cb = (MODE == 2) ? cin + (size_t)b*HWSZ*64 : nullptr;
    const float* stb = (MODE >= 1) ? stin + b*64*2 : nullptr;

    // ---- kv + tap-0 A-frags: independent global loads, overlap staging latency ----
    float kv[9];
    if (HASK) {
#pragma unroll
        for (int t = 0; t < 9; ++t)
            kv[t] = Kb[((size_t)(b*9 + t))*HWSZ + (y0 + wrow)*WW + x0 + ln2];
    }
    const short8* Ap8 = (const short8*)Ap;
    short8 acur[4];
#pragma unroll
    for (int cg = 0; cg < 4; ++cg)
        acur[cg] = Ap8[((size_t)(0*4 + cg)*2 + oh)*64 + lane];

    // ---- per-channel norm coeffs for this thread's fixed c-octet ----
    float mean[8], rstd[8];
    if (MODE >= 1) {
        int c0 = (tid & 7) * 8;
#pragma unroll
        for (int j = 0; j < 8; ++j) {
            float s = stb[(c0+j)*2], s2 = stb[(c0+j)*2+1];
            float m = s * (1.f/HWSZ);
            float var = s2 * (1.f/HWSZ) - m*m;
            mean[j] = m; rstd[j] = rsqrtf(fmaxf(var, 0.f) + EPSV);
        }
    }
    // ---- stage 4 rows x 32 px x 64 c (coalesced 16B chunks) ----
#pragma unroll
    for (int it = 0; it < 4; ++it) {
        int chunk = tid + it*256;                    // 1024 chunks
        int r = chunk >> 8, o = chunk & 255, px = o >> 3, oc = o & 7;
        int yy = refl(y0 - 1 + r, HH);
        size_t base = ((size_t)(yy*WW + x0 + px))*64 + oc*8;
        short8 v = *(const short8*)(hb + base);
        if (MODE == 1) {
#pragma unroll
            for (int j = 0; j < 8; ++j)
                v[j] = f2bf(fmaxf((bf2f(v[j]) - mean[j]) * rstd[j], 0.f));
        } else if (MODE == 2) {
            short8 c = *(const short8*)(cb + base);
#pragma unroll
            for (int j = 0; j < 8; ++j)
                v[j] = f2bf(fmaxf(bf2f(v[j]) + (bf2f(c[j]) - mean[j]) * rstd[j], 0.f));
            if (WRITES && (r == 1 || r == 2))        // own 2 rows x 32 px: write new state
                *(short8*)(snew + (size_t)b*HWSZ*64 + base) = v;
        }
        *(short8*)(lds + (r*34 + 1 + px)*CP + oc*8) = v;
    }
    // ---- halo columns x0-1 and x0+32 (x-reflected at edges; owned by neighbors) ----
    {
        int r = tid >> 6, c = tid & 63;
        int xm = (x0 == 0) ? 1 : x0 - 1;
        int xp = (x0 + 32 == WW) ? WW - 2 : x0 + 32;
        int yy = refl(y0 - 1 + r, HH);
        size_t ba = ((size_t)(yy*WW + xm))*64 + c;
        size_t bb2 = ((size_t)(yy*WW + xp))*64 + c;
        float fa = bf2f(hb[ba]), fb = bf2f(hb[bb2]);
        if (MODE >= 1) {
            float s = stb[c*2], s2 = stb[c*2+1];
            float m = s * (1.f/HWSZ);
            float rs = rsqrtf(fmaxf(s2*(1.f/HWSZ) - m*m, 0.f) + EPSV);
            if (MODE == 1) {
                fa = fmaxf((fa - m)*rs, 0.f);
                fb = fmaxf((fb - m)*rs, 0.f);
            } else {
                fa = fmaxf(fa + (bf2f(cb[ba])  - m)*rs, 0.f);
                fb = fmaxf(fb + (bf2f(cb[bb2]) - m)*rs, 0.f);
            }
        }
        lds[(r*34 + 0)*CP + c]  = f2bf(fa);
        lds[(r*34 + 33)*CP + c] = f2bf(fb);
    }
    __syncthreads();

    // ---- pipelined tap loop ----
    floatx16 acc = (floatx16)(0.f);
    short8 bcur[4];
#pragma unroll
    for (int cg = 0; cg < 4; ++cg)                   // tap 0: dy=-1,dx=-1 -> rr=wrow, col off 0
        bcur[cg] = *(const short8*)(lds + (wrow*34 + ln2)*CP + cg*16 + hi*8);

#pragma unroll
    for (int t = 0; t < 9; ++t) {
        short8 bnx[4], anx[4];
        if (t < 8) {
            int tn = t + 1, dy = tn/3 - 1, dx = tn%3 - 1;
            int rr = wrow + dy + 1;
#pragma unroll
            for (int cg = 0; cg < 4; ++cg) {
                bnx[cg] = *(const short8*)(lds + (rr*34 + 1 + ln2 + dx)*CP + cg*16 + hi*8);
                anx[cg] = Ap8[((size_t)(tn*4 + cg)*2 + oh)*64 + lane];
            }
        }
        if (HASK) {
            floatx16 t0 = (floatx16)(0.f), t1 = (floatx16)(0.f);
            t0 = __builtin_amdgcn_mfma_f32_32x32x16_bf16(acur[0], bcur[0], t0, 0, 0, 0);
            t1 = __builtin_amdgcn_mfma_f32_32x32x16_bf16(acur[2], bcur[2], t1, 0, 0, 0);
            t0 = __builtin_amdgcn_mfma_f32_32x32x16_bf16(acur[1], bcur[1], t0, 0, 0, 0);
            t1 = __builtin_amdgcn_mfma_f32_32x32x16_bf16(acur[3], bcur[3], t1, 0, 0, 0);
            float2v kv2 = {kv[t], kv[t]};
            float2v* a2 = (float2v*)&acc;
            float2v* p0 = (float2v*)&t0;
            float2v* p1 = (float2v*)&t1;
#pragma unroll
            for (int r = 0; r < 8; ++r) a2[r] = __builtin_elementwise_fma(kv2, p0[r], a2[r]);
#pragma unroll
            for (int r = 0; r < 8; ++r) a2[r] = __builtin_elementwise_fma(kv2, p1[r], a2[r]);
        } else {
#pragma unroll
            for (int cg = 0; cg < 4; ++cg)
                acc = __builtin_amdgcn_mfma_f32_32x32x16_bf16(acur[cg], bcur[cg], acc, 0, 0, 0);
        }
#pragma unroll
        for (int cg = 0; cg < 4; ++cg) { bcur[cg] = bnx[cg]; acur[cg] = anx[cg]; }
    }

    // ---- epilogue: C/D col=lane&31 (px), row o = (reg&3)+8*(reg>>2)+4*hi+32*oh ----
    int y = y0 + wrow, x = x0 + ln2;
#pragma unroll
    for (int q = 0; q < 4; ++q) {
        int o0 = oh*32 + hi*4 + 8*q;                 // regs 4q..4q+3 -> o0..o0+3
        float4 bq = *(const float4*)(bias + o0);
        if (FINAL) {
#pragma unroll
            for (int jj = 0; jj < 4; ++jj) {
                float val = acc[q*4 + jj] + ((float*)&bq)[jj];
                val = fmaxf(val, 0.f);
                outf[((size_t)(b*64 + o0 + jj))*HWSZ + y*WW + x] = val;  // NCHW fp32
            }
        } else {
            short4v pk;
#pragma unroll
            for (int jj = 0; jj < 4; ++jj)
                pk[jj] = f2bf(acc[q*4 + jj] + ((float*)&bq)[jj]);
            *(short4v*)(outb + ((size_t)b*HWSZ + (size_t)(y*WW + x))*64 + o0) = pk;
        }
    }
}

// ---------------- stats: per-(b,c) sum/sumsq of bf16 channels-last tensor ----------------
__global__ void __launch_bounds__(256) stats_k(const short* __restrict__ t, float* __restrict__ st){
    int b = blockIdx.y, chunk = blockIdx.x;          // 64 chunks of 1024 px
    int tid = threadIdx.x, oc = tid & 7, pxl = tid >> 3;
    const short* tb = t + (size_t)b*HWSZ*64;
    float s[8] = {0}, s2[8] = {0};
    for (int i = 0; i < 32; ++i) {
        int px = chunk*1024 + i*32 + pxl;
        short8 v = *(const short8*)(tb + (size_t)px*64 + oc*8);
#pragma unroll
        for (int j = 0; j < 8; ++j) { float f = bf2f(v[j]); s[j] += f; s2[j] += f*f; }
    }
#pragma unroll
    for (int mask = 8; mask <= 32; mask <<= 1) {
#pragma unroll
        for (int j = 0; j < 8; ++j) { s[j] += __shfl_xor(s[j], mask); s2[j] += __shfl_xor(s2[j], mask); }
    }
    __shared__ float sm[4][8][16];
    int lane = tid & 63, wave = tid >> 6;
    if (lane < 8) {
#pragma unroll
        for (int j = 0; j < 8; ++j) { sm[wave][lane][j] = s[j]; sm[wave][lane][8+j] = s2[j]; }
    }
    __syncthreads();
    if (tid < 8) {
#pragma unroll
        for (int j = 0; j < 8; ++j) {
            float a = 0, bsq = 0;
#pragma unroll
            for (int w = 0; w < 4; ++w) { a += sm[w][tid][j]; bsq += sm[w][tid][8+j]; }
            atomicAdd(&st[(b*64 + tid*8 + j)*2],     a);
            atomicAdd(&st[(b*64 + tid*8 + j)*2 + 1], bsq);
        }
    }
}

// ---------------- dst <- relu(a + (c - mean)*rstd), bf16 channels-last ----------------
__global__ void addnorm_relu(short* __restrict__ dst, const short* __restrict__ a,
                             const short* __restrict__ c, const float* __restrict__ st){
    int idx = blockIdx.x*256 + threadIdx.x;          // BN*HWSZ*8
    int oc = idx & 7;
    size_t pq = (size_t)(idx >> 3);
    int b = (int)(pq / HWSZ);
    size_t base = pq*64 + oc*8;
    short8 av = *(const short8*)(a + base);
    short8 cv = *(const short8*)(c + base);
#pragma unroll
    for (int j = 0; j < 8; ++j) {
        int cc = oc*8 + j;
        float s = st[(b*64+cc)*2], s2 = st[(b*64+cc)*2+1];
        float m = s * (1.f/HWSZ);
        float rs = rsqrtf(fmaxf(s2*(1.f/HWSZ) - m*m, 0.f) + EPSV);
        float f = bf2f(av[j]) + (bf2f(cv[j]) - m)*rs;
        av[j] = f2bf(fmaxf(f, 0.f));
    }
    *(short8*)(dst + base) = av;
}

extern "C" void kernel_launch(void* const* d_in, const int* in_sizes, int n_in,
                              void* d_out, int out_size, void* d_ws, size_t ws_size,
                              hipStream_t stream) {
    const float* x   = (const float*)d_in[0];
    // d_in[1] = grad_img: unused by the reference
    const float* w0  = (const float*)d_in[2];
    const float* b0  = (const float*)d_in[3];
    const float* wf  = (const float*)d_in[4];
    const float* bf  = (const float*)d_in[5];
    const float* w1a = (const float*)d_in[6];  const float* b1a = (const float*)d_in[7];
    const float* w1b = (const float*)d_in[8];  const float* b1b = (const float*)d_in[9];
    const float* w2a = (const float*)d_in[10]; const float* b2a = (const float*)d_in[11];
    const float* w2b = (const float*)d_in[12]; const float* b2b = (const float*)d_in[13];
    const float* w3a = (const float*)d_in[14]; const float* b3a = (const float*)d_in[15];
    const float* w3b = (const float*)d_in[16]; const float* b3b = (const float*)d_in[17];

    float* ws   = (float*)d_ws;
    float* Kb   = ws;                                 // 2,359,296 f (9.4 MB)
    short* A    = (short*)(Kb + (size_t)BN*9*HWSZ);   // S-state buffer (33.5 MB)
    short* Bb   = A + (size_t)BN*HWSZ*64;             // conv-a output (33.5 MB)
    short* Apk  = Bb + (size_t)BN*HWSZ*64;            // 7*36864 shorts
    float* st   = (float*)(Apk + (size_t)7*36864 + 64); // 6 * 512 floats
    short* Cc   = (short*)d_out;                      // C scratch = d_out half 1 (bf16)
    short* Sp   = Cc + (size_t)BN*HWSZ*64;            // S-ping     = d_out half 2 (bf16)

    zero_stats<<<12, 256, 0, stream>>>(st);
    pack_all<<<dim3(144, 7), 256, 0, stream>>>(w1a, w1b, w2a, w2b, w3a, w3b, wf, Apk);
    guide_kernel<<<(BN*HWSZ + 255)/256, 256, 0, stream>>>(x, Kb);
    conv1x1_kernel<<<BN*HWSZ*8/256, 256, 0, stream>>>(x, w0, b0, A);   // S0 -> A

    dim3 g(WW/32, HH/2, BN);                          // 8 x 128 x 4 = 4096 blocks
    const int eblk = BN*HWSZ*8/256;
    float* st1 = st;            float* stc1 = st + 512;
    float* st2 = st + 1024;     float* stc2 = st + 1536;
    float* st3 = st + 2048;     float* stc3 = st + 2560;

    // ---- resblock 1: S0 in A ----
    pac_mfma<0,1,0,0><<<g,256,0,stream>>>(A,  nullptr, Kb, Apk,            b1a, nullptr, Bb, nullptr, nullptr);
    stats_k<<<dim3(64,BN),256,0,stream>>>(Bb, st1);
    pac_mfma<1,1,0,0><<<g,256,0,stream>>>(Bb, nullptr, Kb, Apk + 36864,    b1b, st1,     Cc, nullptr, nullptr);
    stats_k<<<dim3(64,BN),256,0,stream>>>(Cc, stc1);
    // ---- resblock 2: fused addnorm (S1 = relu(S0+norm(C1))) staged + written to Sp ----
    pac_mfma<2,1,0,1><<<g,256,0,stream>>>(A,  Cc,      Kb, Apk + 2*36864,  b2a, stc1,    Bb, nullptr, Sp);
    stats_k<<<dim3(64,BN),256,0,stream>>>(Bb, st2);
    pac_mfma<1,1,0,0><<<g,256,0,stream>>>(Bb, nullptr, Kb, Apk + 3*36864,  b2b, st2,     Cc, nullptr, nullptr);
    stats_k<<<dim3(64,BN),256,0,stream>>>(Cc, stc2);
    // ---- resblock 3: fused addnorm (S2 = relu(S1+norm(C2))) staged + written to A ----
    pac_mfma<2,1,0,1><<<g,256,0,stream>>>(Sp, Cc,      Kb, Apk + 4*36864,  b3a, stc2,    Bb, nullptr, A);
    stats_k<<<dim3(64,BN),256,0,stream>>>(Bb, st3);
    pac_mfma<1,1,0,0><<<g,256,0,stream>>>(Bb, nullptr, Kb, Apk + 5*36864,  b3b, st3,     Cc, nullptr, nullptr);
    stats_k<<<dim3(64,BN),256,0,stream>>>(Cc, stc3);
    // ---- last addnorm standalone (S3 -> Bb), so final pac can own all of d_out ----
    addnorm_relu<<<eblk,256,0,stream>>>(Bb, A, Cc, stc3);
    // ---- final: plain 3x3 conv (no K), bias+relu, fp32 NCHW -> d_out ----
    pac_mfma<0,0,1,0><<<g,256,0,stream>>>(Bb, nullptr, Kb, Apk + 6*36864,  bf,  nullptr, nullptr, (float*)d_out, nullptr);
}

// Round 8
// 585.030 us; speedup vs baseline: 1.7276x; 1.0412x over previous
//
#include <hip/hip_runtime.h>
#include <hip/hip_bf16.h>
#include <math.h>

#define BN 4
#define CHN 64
#define HH 256
#define WW 256
#define HWSZ (HH*WW)
#define EPSV 1e-5f
#define CP 72   // LDS px-row stride in shorts (144 B): 16B-aligned, 0 conflicts (r4-measured)

typedef __attribute__((ext_vector_type(8)))  short  short8;
typedef __attribute__((ext_vector_type(4)))  short  short4v;
typedef __attribute__((ext_vector_type(16))) float  floatx16;

__device__ __forceinline__ int refl(int i, int n){ if(i<0)i=-i; if(i>=n)i=2*n-2-i; return i; }
__device__ __forceinline__ short f2bf(float f){ __hip_bfloat16 h=__float2bfloat16(f); return __builtin_bit_cast(short,h); }
__device__ __forceinline__ float bf2f(short s){ unsigned u=((unsigned)(unsigned short)s)<<16; return __builtin_bit_cast(float,u); }

// ---------------- pack all 7 weight tensors into 32x32x16 A-fragment order ----------------
// frag = (t*4+cg)*2+oh ; o = oh*32+(lane&31) ; c = cg*16+(lane>>5)*8+j
// Also zeroes the 6x[4][64][2] stats accumulators (d_ws is poisoned before every launch).
__global__ void pack_all(const float* w1,const float* w2,const float* w3,const float* w4,
                         const float* w5,const float* w6,const float* w7,
                         short* __restrict__ Ap, float* __restrict__ st){
    const float* wsrc[7] = {w1,w2,w3,w4,w5,w6,w7};
    int layer = blockIdx.y;
    int tid = blockIdx.x*256 + threadIdx.x;          // 0..36863
    if (layer == 0 && tid < 6*BN*64*2) st[tid] = 0.f;
    int j    = tid & 7;
    int lane = (tid >> 3) & 63;
    int frag = tid >> 9;                             // 0..71
    int oh = frag & 1, cg = (frag >> 1) & 3, t = frag >> 3;
    int o = oh*32 + (lane & 31);
    int c = cg*16 + (lane >> 5)*8 + j;
    Ap[(size_t)layer*36864 + tid] = f2bf(wsrc[layer][(o*CHN + c)*9 + t]);
}

// ---------------- conv1x1 -> S0, channels-last bf16 [b][y][x][c] ----------------
__global__ void conv1x1_kernel(const float* __restrict__ x, const float* __restrict__ w0,
                               const float* __restrict__ b0, short* __restrict__ A){
    int idx = blockIdx.x*256 + threadIdx.x;          // BN*HWSZ*8 (px-octets)
    int oc = idx & 7;
    int px = (idx >> 3) % HWSZ;
    int b  = idx / (HWSZ*8);
    float xv = x[(size_t)b*HWSZ + px];
    short8 r;
#pragma unroll
    for (int j = 0; j < 8; ++j) {
        int c = oc*8 + j;
        r[j] = f2bf(fmaf(w0[c], xv, b0[c]));
    }
    *(short8*)(A + ((size_t)(b*HWSZ + px))*64 + oc*8) = r;
}

// ---------------- PAC conv, implicit GEMM on mfma_32x32x16_bf16 ----------------
// r4-proven structure: block = 64 o x (32 px x 2 rows); waves (oh = w&1, wrow = w>>1).
// Guide folded in: kv[t] = exp(-0.5*(g_shift - g)^2) computed from x directly
// (10 coalesced fp32 loads + 9 v_exp per lane) -- no Kb tensor at all.
// MODE 0: stage hin raw.  MODE 1: stage relu(norm(hin)) from stin.
// MODE 2: stage relu(hin + norm(cin)); designated-write own pixels (rows r=1,2) to snew.
// Tap loop: byte-exact r4 inner loop (single tmp chain, per-cg load->mfma, scalar
// fmaf K-apply) -- the only variant measured at 47 us.
template<int MODE, int HASK, int FINAL, int WRITES>
__global__ void __launch_bounds__(256, 3) pac_mfma(
    const short* __restrict__ hin, const short* __restrict__ cin,
    const float* __restrict__ xg,
    const short* __restrict__ Ap, const float* __restrict__ bias,
    const float* __restrict__ stin, short* __restrict__ outb, float* __restrict__ outf,
    short* __restrict__ snew)
{
    __shared__ short lds[4*34*CP];                   // 19584 B

    int b  = blockIdx.z;
    int y0 = blockIdx.y * 2;
    int x0 = blockIdx.x * 32;
    int tid = threadIdx.x, lane = tid & 63, wave = tid >> 6;
    int ln2 = lane & 31, hi = lane >> 5, oh = wave & 1, wrow = wave >> 1;
    const short* hb = hin + (size_t)b*HWSZ*64;
    const short* cb = (MODE == 2) ? cin + (size_t)b*HWSZ*64 : nullptr;
    const float* stb = (MODE >= 1) ? stin + b*64*2 : nullptr;

    // ---- kv from guide x (hoisted: independent loads overlap staging latency) ----
    float kv[9];
    if (HASK) {
        const float* gx = xg + (size_t)b*HWSZ;
        int y = y0 + wrow, xx = x0 + ln2;
        float gc = gx[y*WW + xx];
#pragma unroll
        for (int t = 0; t < 9; ++t) {
            int yy  = refl(y + t/3 - 1, HH);
            int xx2 = refl(xx + t%3 - 1, WW);
            float d = gx[yy*WW + xx2] - gc;
            kv[t] = __expf(-0.5f*d*d);
        }
    }

    // ---- per-channel norm coeffs for this thread's fixed c-octet ----
    float mean[8], rstd[8];
    if (MODE >= 1) {
        int c0 = (tid & 7) * 8;
#pragma unroll
        for (int j = 0; j < 8; ++j) {
            float s = stb[(c0+j)*2], s2 = stb[(c0+j)*2+1];
            float m = s * (1.f/HWSZ);
            float var = s2 * (1.f/HWSZ) - m*m;
            mean[j] = m; rstd[j] = rsqrtf(fmaxf(var, 0.f) + EPSV);
        }
    }
    // ---- stage 4 rows x 32 px x 64 c (coalesced 16B chunks) ----
#pragma unroll
    for (int it = 0; it < 4; ++it) {
        int chunk = tid + it*256;                    // 1024 chunks
        int r = chunk >> 8, o = chunk & 255, px = o >> 3, oc = o & 7;
        int yy = refl(y0 - 1 + r, HH);
        size_t base = ((size_t)(yy*WW + x0 + px))*64 + oc*8;
        short8 v = *(const short8*)(hb + base);
        if (MODE == 1) {
#pragma unroll
            for (int j = 0; j < 8; ++j)
                v[j] = f2bf(fmaxf((bf2f(v[j]) - mean[j]) * rstd[j], 0.f));
        } else if (MODE == 2) {
            short8 c = *(const short8*)(cb + base);
#pragma unroll
            for (int j = 0; j < 8; ++j)
                v[j] = f2bf(fmaxf(bf2f(v[j]) + (bf2f(c[j]) - mean[j]) * rstd[j], 0.f));
            if (WRITES && (r == 1 || r == 2))        // own 2 rows x 32 px: write new state
                *(short8*)(snew + (size_t)b*HWSZ*64 + base) = v;
        }
        *(short8*)(lds + (r*34 + 1 + px)*CP + oc*8) = v;
    }
    // ---- halo columns x0-1 and x0+32 (x-reflected at edges) ----
    {
        int r = tid >> 6, c = tid & 63;
        int xm = (x0 == 0) ? 1 : x0 - 1;
        int xp = (x0 + 32 == WW) ? WW - 2 : x0 + 32;
        int yy = refl(y0 - 1 + r, HH);
        size_t ba = ((size_t)(yy*WW + xm))*64 + c;
        size_t bb2 = ((size_t)(yy*WW + xp))*64 + c;
        float fa = bf2f(hb[ba]), fb = bf2f(hb[bb2]);
        if (MODE >= 1) {
            float s = stb[c*2], s2 = stb[c*2+1];
            float m = s * (1.f/HWSZ);
            float rs = rsqrtf(fmaxf(s2*(1.f/HWSZ) - m*m, 0.f) + EPSV);
            if (MODE == 1) {
                fa = fmaxf((fa - m)*rs, 0.f);
                fb = fmaxf((fb - m)*rs, 0.f);
            } else {
                fa = fmaxf(fa + (bf2f(cb[ba])  - m)*rs, 0.f);
                fb = fmaxf(fb + (bf2f(cb[bb2]) - m)*rs, 0.f);
            }
        }
        lds[(r*34 + 0)*CP + c]  = f2bf(fa);
        lds[(r*34 + 33)*CP + c] = f2bf(fb);
    }
    __syncthreads();

    // ---- tap loop (r4-exact) ----
    floatx16 acc = (floatx16)(0.f);
    const short8* Ap8 = (const short8*)Ap;
#pragma unroll
    for (int t = 0; t < 9; ++t) {
        int dy = t/3 - 1, dx = t%3 - 1;
        int rr = wrow + dy + 1;                      // 0..3
        if (HASK) {
            floatx16 tmp;
#pragma unroll
            for (int cg = 0; cg < 4; ++cg) {
                short8 bfr = *(const short8*)(lds + (rr*34 + 1 + ln2 + dx)*CP + cg*16 + hi*8);
                short8 af  = Ap8[((size_t)(t*4 + cg)*2 + oh)*64 + lane];
                tmp = __builtin_amdgcn_mfma_f32_32x32x16_bf16(af, bfr, cg == 0 ? (floatx16)(0.f) : tmp, 0, 0, 0);
            }
#pragma unroll
            for (int r = 0; r < 16; ++r) acc[r] = fmaf(kv[t], tmp[r], acc[r]);
        } else {
#pragma unroll
            for (int cg = 0; cg < 4; ++cg) {
                short8 bfr = *(const short8*)(lds + (rr*34 + 1 + ln2 + dx)*CP + cg*16 + hi*8);
                short8 af  = Ap8[((size_t)(t*4 + cg)*2 + oh)*64 + lane];
                acc = __builtin_amdgcn_mfma_f32_32x32x16_bf16(af, bfr, acc, 0, 0, 0);
            }
        }
    }

    // ---- epilogue: C/D col=lane&31 (px), row o = (reg&3)+8*(reg>>2)+4*hi+32*oh ----
    int y = y0 + wrow, x = x0 + ln2;
#pragma unroll
    for (int q = 0; q < 4; ++q) {
        int o0 = oh*32 + hi*4 + 8*q;                 // regs 4q..4q+3 -> o0..o0+3
        float4 bq = *(const float4*)(bias + o0);
        if (FINAL) {
#pragma unroll
            for (int jj = 0; jj < 4; ++jj) {
                float val = acc[q*4 + jj] + ((float*)&bq)[jj];
                val = fmaxf(val, 0.f);
                outf[((size_t)(b*64 + o0 + jj))*HWSZ + y*WW + x] = val;  // NCHW fp32
            }
        } else {
            short4v pk;
#pragma unroll
            for (int jj = 0; jj < 4; ++jj)
                pk[jj] = f2bf(acc[q*4 + jj] + ((float*)&bq)[jj]);
            *(short4v*)(outb + ((size_t)b*HWSZ + (size_t)(y*WW + x))*64 + o0) = pk;
        }
    }
}

// ---------------- stats: per-(b,c) sum/sumsq of bf16 channels-last tensor ----------------
__global__ void __launch_bounds__(256) stats_k(const short* __restrict__ t, float* __restrict__ st){
    int b = blockIdx.y, chunk = blockIdx.x;          // 64 chunks of 1024 px
    int tid = threadIdx.x, oc = tid & 7, pxl = tid >> 3;
    const short* tb = t + (size_t)b*HWSZ*64;
    float s[8] = {0}, s2[8] = {0};
    for (int i = 0; i < 32; ++i) {
        int px = chunk*1024 + i*32 + pxl;
        short8 v = *(const short8*)(tb + (size_t)px*64 + oc*8);
#pragma unroll
        for (int j = 0; j < 8; ++j) { float f = bf2f(v[j]); s[j] += f; s2[j] += f*f; }
    }
#pragma unroll
    for (int mask = 8; mask <= 32; mask <<= 1) {
#pragma unroll
        for (int j = 0; j < 8; ++j) { s[j] += __shfl_xor(s[j], mask); s2[j] += __shfl_xor(s2[j], mask); }
    }
    __shared__ float sm[4][8][16];
    int lane = tid & 63, wave = tid >> 6;
    if (lane < 8) {
#pragma unroll
        for (int j = 0; j < 8; ++j) { sm[wave][lane][j] = s[j]; sm[wave][lane][8+j] = s2[j]; }
    }
    __syncthreads();
    if (tid < 8) {
#pragma unroll
        for (int j = 0; j < 8; ++j) {
            float a = 0, bsq = 0;
#pragma unroll
            for (int w = 0; w < 4; ++w) { a += sm[w][tid][j]; bsq += sm[w][tid][8+j]; }
            atomicAdd(&st[(b*64 + tid*8 + j)*2],     a);
            atomicAdd(&st[(b*64 + tid*8 + j)*2 + 1], bsq);
        }
    }
}

// ---------------- dst <- relu(a + (c - mean)*rstd), bf16 channels-last ----------------
__global__ void addnorm_relu(short* __restrict__ dst, const short* __restrict__ a,
                             const short* __restrict__ c, const float* __restrict__ st){
    int idx = blockIdx.x*256 + threadIdx.x;          // BN*HWSZ*8
    int oc = idx & 7;
    size_t pq = (size_t)(idx >> 3);
    int b = (int)(pq / HWSZ);
    size_t base = pq*64 + oc*8;
    short8 av = *(const short8*)(a + base);
    short8 cv = *(const short8*)(c + base);
#pragma unroll
    for (int j = 0; j < 8; ++j) {
        int cc = oc*8 + j;
        float s = st[(b*64+cc)*2], s2 = st[(b*64+cc)*2+1];
        float m = s * (1.f/HWSZ);
        float rs = rsqrtf(fmaxf(s2*(1.f/HWSZ) - m*m, 0.f) + EPSV);
        float f = bf2f(av[j]) + (bf2f(cv[j]) - m)*rs;
        av[j] = f2bf(fmaxf(f, 0.f));
    }
    *(short8*)(dst + base) = av;
}

extern "C" void kernel_launch(void* const* d_in, const int* in_sizes, int n_in,
                              void* d_out, int out_size, void* d_ws, size_t ws_size,
                              hipStream_t stream) {
    const float* x   = (const float*)d_in[0];
    // d_in[1] = grad_img: unused by the reference
    const float* w0  = (const float*)d_in[2];
    const float* b0  = (const float*)d_in[3];
    const float* wf  = (const float*)d_in[4];
    const float* bf  = (const float*)d_in[5];
    const float* w1a = (const float*)d_in[6];  const float* b1a = (const float*)d_in[7];
    const float* w1b = (const float*)d_in[8];  const float* b1b = (const float*)d_in[9];
    const float* w2a = (const float*)d_in[10]; const float* b2a = (const float*)d_in[11];
    const float* w2b = (const float*)d_in[12]; const float* b2b = (const float*)d_in[13];
    const float* w3a = (const float*)d_in[14]; const float* b3a = (const float*)d_in[15];
    const float* w3b = (const float*)d_in[16]; const float* b3b = (const float*)d_in[17];

    short* A    = (short*)d_ws;                       // S-state (33.5 MB)
    short* Bb   = A + (size_t)BN*HWSZ*64;             // conv-a outputs (33.5 MB)
    short* Apk  = Bb + (size_t)BN*HWSZ*64;            // 7*36864 shorts
    float* st   = (float*)(Apk + (size_t)7*36864 + 64); // 6 * 512 floats
    short* D1   = (short*)d_out;                      // d_out half 1 (bf16 scratch)
    short* D2   = D1 + (size_t)BN*HWSZ*64;            // d_out half 2 (bf16 scratch)

    pack_all<<<dim3(144, 7), 256, 0, stream>>>(w1a, w1b, w2a, w2b, w3a, w3b, wf, Apk, st);
    conv1x1_kernel<<<BN*HWSZ*8/256, 256, 0, stream>>>(x, w0, b0, A);   // S0 -> A

    dim3 g(WW/32, HH/2, BN);                          // 8 x 128 x 4 = 4096 blocks
    const int eblk = BN*HWSZ*8/256;
    float* st1 = st;            float* stc1 = st + 512;
    float* st2 = st + 1024;     float* stc2 = st + 1536;
    float* st3 = st + 2048;     float* stc3 = st + 2560;

    // ---- resblock 1 ----
    pac_mfma<0,1,0,0><<<g,256,0,stream>>>(A,  nullptr, x, Apk,           b1a, nullptr, Bb, nullptr, nullptr);
    stats_k<<<dim3(64,BN),256,0,stream>>>(Bb, st1);
    pac_mfma<1,1,0,0><<<g,256,0,stream>>>(Bb, nullptr, x, Apk + 36864,   b1b, st1,     D1, nullptr, nullptr);
    stats_k<<<dim3(64,BN),256,0,stream>>>(D1, stc1);
    // ---- resblock 2: fused addnorm stages S1 = relu(S0+norm(C1)), writes S1 -> D2 ----
    pac_mfma<2,1,0,1><<<g,256,0,stream>>>(A,  D1,      x, Apk + 2*36864, b2a, stc1,    Bb, nullptr, D2);
    stats_k<<<dim3(64,BN),256,0,stream>>>(Bb, st2);
    pac_mfma<1,1,0,0><<<g,256,0,stream>>>(Bb, nullptr, x, Apk + 3*36864, b2b, st2,     D1, nullptr, nullptr);
    stats_k<<<dim3(64,BN),256,0,stream>>>(D1, stc2);
    // ---- resblock 3: fused addnorm stages S2 = relu(S1+norm(C2)), writes S2 -> A ----
    pac_mfma<2,1,0,1><<<g,256,0,stream>>>(D2, D1,      x, Apk + 4*36864, b3a, stc2,    Bb, nullptr, A);
    stats_k<<<dim3(64,BN),256,0,stream>>>(Bb, st3);
    pac_mfma<1,1,0,0><<<g,256,0,stream>>>(Bb, nullptr, x, Apk + 5*36864, b3b, st3,     D1, nullptr, nullptr);
    stats_k<<<dim3(64,BN),256,0,stream>>>(D1, stc3);
    // ---- last addnorm standalone (S3 -> Bb) so the final pac owns all of d_out ----
    addnorm_relu<<<eblk,256,0,stream>>>(Bb, A, D1, stc3);
    // ---- final: plain 3x3 conv (no K), bias+relu, fp32 NCHW -> d_out ----
    pac_mfma<0,0,1,0><<<g,256,0,stream>>>(Bb, nullptr, x, Apk + 6*36864, bf,  nullptr, nullptr, (float*)d_out, nullptr);
}

// Round 9
// 563.569 us; speedup vs baseline: 1.7934x; 1.0381x over previous
//
#include <hip/hip_runtime.h>
#include <hip/hip_bf16.h>
#include <math.h>

#define BN 4
#define CHN 64
#define HH 256
#define WW 256
#define HWSZ (HH*WW)
#define EPSV 1e-5f
#define CP 72   // LDS px-row stride in shorts (144 B): 16B-aligned, 0 conflicts (r4-measured)

typedef __attribute__((ext_vector_type(8)))  short  short8;
typedef __attribute__((ext_vector_type(4)))  short  short4v;
typedef __attribute__((ext_vector_type(16))) float  floatx16;

__device__ __forceinline__ int refl(int i, int n){ if(i<0)i=-i; if(i>=n)i=2*n-2-i; return i; }
__device__ __forceinline__ short f2bf(float f){ __hip_bfloat16 h=__float2bfloat16(f); return __builtin_bit_cast(short,h); }
__device__ __forceinline__ float bf2f(short s){ unsigned u=((unsigned)(unsigned short)s)<<16; return __builtin_bit_cast(float,u); }

// ---------------- pack all 7 weight tensors into 32x32x16 A-fragment order ----------------
// frag = (t*4+cg)*2+oh ; o = oh*32+(lane&31) ; c = cg*16+(lane>>5)*8+j
// Also zeroes the 6x[4][64][2] stats accumulators (d_ws is poisoned before every launch).
__global__ void pack_all(const float* w1,const float* w2,const float* w3,const float* w4,
                         const float* w5,const float* w6,const float* w7,
                         short* __restrict__ Ap, float* __restrict__ st){
    const float* wsrc[7] = {w1,w2,w3,w4,w5,w6,w7};
    int layer = blockIdx.y;
    int tid = blockIdx.x*256 + threadIdx.x;          // 0..36863
    if (layer == 0 && tid < 6*BN*64*2) st[tid] = 0.f;
    int j    = tid & 7;
    int lane = (tid >> 3) & 63;
    int frag = tid >> 9;                             // 0..71
    int oh = frag & 1, cg = (frag >> 1) & 3, t = frag >> 3;
    int o = oh*32 + (lane & 31);
    int c = cg*16 + (lane >> 5)*8 + j;
    Ap[(size_t)layer*36864 + tid] = f2bf(wsrc[layer][(o*CHN + c)*9 + t]);
}

// ---------------- PAC conv, implicit GEMM on mfma_32x32x16_bf16 ----------------
// r4-proven structure: block = 64 o x (32 px x 2 rows); waves (oh = w&1, wrow = w>>1).
// Guide folded in: kv[t] = exp(-0.5*(g_shift - g)^2) computed from x directly.
// MODE 0: stage hin raw.
// MODE 1: stage relu(norm(hin)) from stin.
// MODE 2: stage relu(hin + norm(cin)) from stin (fused addnorm).
// MODE 3: stage conv1x1(x) = w0[c]*x+b0[c] (fused stem conv; hin unused).
// WRITES: designated-write own pixels (rows r=1,2) of the staged state to snew.
// Tap loop: byte-exact r4 inner loop -- the only variant measured at 47 us.
template<int MODE, int HASK, int FINAL, int WRITES>
__global__ void __launch_bounds__(256, 3) pac_mfma(
    const short* __restrict__ hin, const short* __restrict__ cin,
    const float* __restrict__ xg,
    const short* __restrict__ Ap, const float* __restrict__ bias,
    const float* __restrict__ stin, short* __restrict__ outb, float* __restrict__ outf,
    short* __restrict__ snew, const float* __restrict__ w0g, const float* __restrict__ b0g)
{
    __shared__ short lds[4*34*CP];                   // 19584 B

    int b  = blockIdx.z;
    int y0 = blockIdx.y * 2;
    int x0 = blockIdx.x * 32;
    int tid = threadIdx.x, lane = tid & 63, wave = tid >> 6;
    int ln2 = lane & 31, hi = lane >> 5, oh = wave & 1, wrow = wave >> 1;
    const short* hb = (MODE != 3) ? hin + (size_t)b*HWSZ*64 : nullptr;
    const short* cb = (MODE == 2) ? cin + (size_t)b*HWSZ*64 : nullptr;
    const float* stb = (MODE == 1 || MODE == 2) ? stin + b*64*2 : nullptr;
    const float* xga = xg + (size_t)b*HWSZ;

    // ---- kv from guide x (hoisted: independent loads overlap staging latency) ----
    float kv[9];
    if (HASK) {
        int y = y0 + wrow, xx = x0 + ln2;
        float gc = xga[y*WW + xx];
#pragma unroll
        for (int t = 0; t < 9; ++t) {
            int yy  = refl(y + t/3 - 1, HH);
            int xx2 = refl(xx + t%3 - 1, WW);
            float d = xga[yy*WW + xx2] - gc;
            kv[t] = __expf(-0.5f*d*d);
        }
    }

    // ---- per-channel coeffs for this thread's fixed c-octet ----
    float mean[8], rstd[8];                          // MODE1/2: norm coeffs
    float w0v[8], b0v[8];                            // MODE3: conv1x1 coeffs
    {
        int c0 = (tid & 7) * 8;
        if (MODE == 1 || MODE == 2) {
#pragma unroll
            for (int j = 0; j < 8; ++j) {
                float s = stb[(c0+j)*2], s2 = stb[(c0+j)*2+1];
                float m = s * (1.f/HWSZ);
                float var = s2 * (1.f/HWSZ) - m*m;
                mean[j] = m; rstd[j] = rsqrtf(fmaxf(var, 0.f) + EPSV);
            }
        } else if (MODE == 3) {
#pragma unroll
            for (int j = 0; j < 8; ++j) { w0v[j] = w0g[c0+j]; b0v[j] = b0g[c0+j]; }
        }
    }
    // ---- stage 4 rows x 32 px x 64 c (coalesced 16B chunks) ----
#pragma unroll
    for (int it = 0; it < 4; ++it) {
        int chunk = tid + it*256;                    // 1024 chunks
        int r = chunk >> 8, o = chunk & 255, px = o >> 3, oc = o & 7;
        int yy = refl(y0 - 1 + r, HH);
        size_t base = ((size_t)(yy*WW + x0 + px))*64 + oc*8;
        short8 v;
        if (MODE == 3) {
            float xv = xga[yy*WW + x0 + px];
#pragma unroll
            for (int j = 0; j < 8; ++j) v[j] = f2bf(fmaf(w0v[j], xv, b0v[j]));
        } else {
            v = *(const short8*)(hb + base);
            if (MODE == 1) {
#pragma unroll
                for (int j = 0; j < 8; ++j)
                    v[j] = f2bf(fmaxf((bf2f(v[j]) - mean[j]) * rstd[j], 0.f));
            } else if (MODE == 2) {
                short8 c = *(const short8*)(cb + base);
#pragma unroll
                for (int j = 0; j < 8; ++j)
                    v[j] = f2bf(fmaxf(bf2f(v[j]) + (bf2f(c[j]) - mean[j]) * rstd[j], 0.f));
            }
        }
        if (WRITES && (r == 1 || r == 2))            // own 2 rows x 32 px: write new state
            *(short8*)(snew + (size_t)b*HWSZ*64 + base) = v;
        *(short8*)(lds + (r*34 + 1 + px)*CP + oc*8) = v;
    }
    // ---- halo columns x0-1 and x0+32 (x-reflected at edges; pointwise ops commute) ----
    {
        int r = tid >> 6, c = tid & 63;
        int xm = (x0 == 0) ? 1 : x0 - 1;
        int xp = (x0 + 32 == WW) ? WW - 2 : x0 + 32;
        int yy = refl(y0 - 1 + r, HH);
        float fa, fb;
        if (MODE == 3) {
            float wv = w0g[c], bv = b0g[c];
            fa = fmaf(wv, xga[yy*WW + xm], bv);
            fb = fmaf(wv, xga[yy*WW + xp], bv);
        } else {
            size_t ba = ((size_t)(yy*WW + xm))*64 + c;
            size_t bb2 = ((size_t)(yy*WW + xp))*64 + c;
            fa = bf2f(hb[ba]); fb = bf2f(hb[bb2]);
            if (MODE == 1 || MODE == 2) {
                float s = stb[c*2], s2 = stb[c*2+1];
                float m = s * (1.f/HWSZ);
                float rs = rsqrtf(fmaxf(s2*(1.f/HWSZ) - m*m, 0.f) + EPSV);
                if (MODE == 1) {
                    fa = fmaxf((fa - m)*rs, 0.f);
                    fb = fmaxf((fb - m)*rs, 0.f);
                } else {
                    fa = fmaxf(fa + (bf2f(cb[ba])  - m)*rs, 0.f);
                    fb = fmaxf(fb + (bf2f(cb[bb2]) - m)*rs, 0.f);
                }
            }
        }
        lds[(r*34 + 0)*CP + c]  = f2bf(fa);
        lds[(r*34 + 33)*CP + c] = f2bf(fb);
    }
    __syncthreads();

    // ---- tap loop (r4-exact) ----
    floatx16 acc = (floatx16)(0.f);
    const short8* Ap8 = (const short8*)Ap;
#pragma unroll
    for (int t = 0; t < 9; ++t) {
        int dy = t/3 - 1, dx = t%3 - 1;
        int rr = wrow + dy + 1;                      // 0..3
        if (HASK) {
            floatx16 tmp;
#pragma unroll
            for (int cg = 0; cg < 4; ++cg) {
                short8 bfr = *(const short8*)(lds + (rr*34 + 1 + ln2 + dx)*CP + cg*16 + hi*8);
                short8 af  = Ap8[((size_t)(t*4 + cg)*2 + oh)*64 + lane];
                tmp = __builtin_amdgcn_mfma_f32_32x32x16_bf16(af, bfr, cg == 0 ? (floatx16)(0.f) : tmp, 0, 0, 0);
            }
#pragma unroll
            for (int r = 0; r < 16; ++r) acc[r] = fmaf(kv[t], tmp[r], acc[r]);
        } else {
#pragma unroll
            for (int cg = 0; cg < 4; ++cg) {
                short8 bfr = *(const short8*)(lds + (rr*34 + 1 + ln2 + dx)*CP + cg*16 + hi*8);
                short8 af  = Ap8[((size_t)(t*4 + cg)*2 + oh)*64 + lane];
                acc = __builtin_amdgcn_mfma_f32_32x32x16_bf16(af, bfr, acc, 0, 0, 0);
            }
        }
    }

    // ---- epilogue: C/D col=lane&31 (px), row o = (reg&3)+8*(reg>>2)+4*hi+32*oh ----
    int y = y0 + wrow, x = x0 + ln2;
#pragma unroll
    for (int q = 0; q < 4; ++q) {
        int o0 = oh*32 + hi*4 + 8*q;                 // regs 4q..4q+3 -> o0..o0+3
        float4 bq = *(const float4*)(bias + o0);
        if (FINAL) {
#pragma unroll
            for (int jj = 0; jj < 4; ++jj) {
                float val = acc[q*4 + jj] + ((float*)&bq)[jj];
                val = fmaxf(val, 0.f);
                outf[((size_t)(b*64 + o0 + jj))*HWSZ + y*WW + x] = val;  // NCHW fp32
            }
        } else {
            short4v pk;
#pragma unroll
            for (int jj = 0; jj < 4; ++jj)
                pk[jj] = f2bf(acc[q*4 + jj] + ((float*)&bq)[jj]);
            *(short4v*)(outb + ((size_t)b*HWSZ + (size_t)(y*WW + x))*64 + o0) = pk;
        }
    }
}

// ---------------- stats: per-(b,c) sum/sumsq of bf16 channels-last tensor ----------------
__global__ void __launch_bounds__(256) stats_k(const short* __restrict__ t, float* __restrict__ st){
    int b = blockIdx.y, chunk = blockIdx.x;          // 64 chunks of 1024 px
    int tid = threadIdx.x, oc = tid & 7, pxl = tid >> 3;
    const short* tb = t + (size_t)b*HWSZ*64;
    float s[8] = {0}, s2[8] = {0};
    for (int i = 0; i < 32; ++i) {
        int px = chunk*1024 + i*32 + pxl;
        short8 v = *(const short8*)(tb + (size_t)px*64 + oc*8);
#pragma unroll
        for (int j = 0; j < 8; ++j) { float f = bf2f(v[j]); s[j] += f; s2[j] += f*f; }
    }
#pragma unroll
    for (int mask = 8; mask <= 32; mask <<= 1) {
#pragma unroll
        for (int j = 0; j < 8; ++j) { s[j] += __shfl_xor(s[j], mask); s2[j] += __shfl_xor(s2[j], mask); }
    }
    __shared__ float sm[4][8][16];
    int lane = tid & 63, wave = tid >> 6;
    if (lane < 8) {
#pragma unroll
        for (int j = 0; j < 8; ++j) { sm[wave][lane][j] = s[j]; sm[wave][lane][8+j] = s2[j]; }
    }
    __syncthreads();
    if (tid < 8) {
#pragma unroll
        for (int j = 0; j < 8; ++j) {
            float a = 0, bsq = 0;
#pragma unroll
            for (int w = 0; w < 4; ++w) { a += sm[w][tid][j]; bsq += sm[w][tid][8+j]; }
            atomicAdd(&st[(b*64 + tid*8 + j)*2],     a);
            atomicAdd(&st[(b*64 + tid*8 + j)*2 + 1], bsq);
        }
    }
}

extern "C" void kernel_launch(void* const* d_in, const int* in_sizes, int n_in,
                              void* d_out, int out_size, void* d_ws, size_t ws_size,
                              hipStream_t stream) {
    const float* x   = (const float*)d_in[0];
    // d_in[1] = grad_img: unused by the reference
    const float* w0  = (const float*)d_in[2];
    const float* b0  = (const float*)d_in[3];
    const float* wf  = (const float*)d_in[4];
    const float* bf  = (const float*)d_in[5];
    const float* w1a = (const float*)d_in[6];  const float* b1a = (const float*)d_in[7];
    const float* w1b = (const float*)d_in[8];  const float* b1b = (const float*)d_in[9];
    const float* w2a = (const float*)d_in[10]; const float* b2a = (const float*)d_in[11];
    const float* w2b = (const float*)d_in[12]; const float* b2b = (const float*)d_in[13];
    const float* w3a = (const float*)d_in[14]; const float* b3a = (const float*)d_in[15];
    const float* w3b = (const float*)d_in[16]; const float* b3b = (const float*)d_in[17];

    // ws: S-state + C-conv outputs (FINAL reads only ws -> no d_out read/write race)
    short* Sb   = (short*)d_ws;                       // S-state (33.5 MB)
    short* Cc   = Sb + (size_t)BN*HWSZ*64;            // C-conv outputs (33.5 MB)
    short* Apk  = Cc + (size_t)BN*HWSZ*64;            // 7*36864 shorts
    float* st   = (float*)(Apk + (size_t)7*36864 + 64); // 6 * 512 floats
    // d_out halves: both dead before the FINAL pac writes fp32 output
    short* Bb   = (short*)d_out;                      // B-conv outputs (bf16 scratch)
    short* Sp   = Bb + (size_t)BN*HWSZ*64;            // S-ping (bf16 scratch)

    pack_all<<<dim3(144, 7), 256, 0, stream>>>(w1a, w1b, w2a, w2b, w3a, w3b, wf, Apk, st);

    dim3 g(WW/32, HH/2, BN);                          // 8 x 128 x 4 = 4096 blocks
    float* st1 = st;            float* stc1 = st + 512;
    float* st2 = st + 1024;     float* stc2 = st + 1536;
    float* st3 = st + 2048;     float* stc3 = st + 2560;

    // ---- resblock 1: pac1 fuses conv1x1 stem (MODE3), writes S0 -> Sb, conv B1 -> Bb ----
    pac_mfma<3,1,0,1><<<g,256,0,stream>>>(nullptr, nullptr, x, Apk,           b1a, nullptr, Bb, nullptr, Sb, w0, b0);
    stats_k<<<dim3(64,BN),256,0,stream>>>(Bb, st1);
    pac_mfma<1,1,0,0><<<g,256,0,stream>>>(Bb, nullptr, x, Apk + 36864,   b1b, st1,     Cc, nullptr, nullptr, nullptr, nullptr);
    stats_k<<<dim3(64,BN),256,0,stream>>>(Cc, stc1);
    // ---- resblock 2: fused addnorm stages S1 = relu(S0+norm(C1)), writes S1 -> Sp ----
    pac_mfma<2,1,0,1><<<g,256,0,stream>>>(Sb, Cc,      x, Apk + 2*36864, b2a, stc1,    Bb, nullptr, Sp, nullptr, nullptr);
    stats_k<<<dim3(64,BN),256,0,stream>>>(Bb, st2);
    pac_mfma<1,1,0,0><<<g,256,0,stream>>>(Bb, nullptr, x, Apk + 3*36864, b2b, st2,     Cc, nullptr, nullptr, nullptr, nullptr);
    stats_k<<<dim3(64,BN),256,0,stream>>>(Cc, stc2);
    // ---- resblock 3: fused addnorm stages S2 = relu(S1+norm(C2)), writes S2 -> Sb ----
    pac_mfma<2,1,0,1><<<g,256,0,stream>>>(Sp, Cc,      x, Apk + 4*36864, b3a, stc2,    Bb, nullptr, Sb, nullptr, nullptr);
    stats_k<<<dim3(64,BN),256,0,stream>>>(Bb, st3);
    pac_mfma<1,1,0,0><<<g,256,0,stream>>>(Bb, nullptr, x, Apk + 5*36864, b3b, st3,     Cc, nullptr, nullptr, nullptr, nullptr);
    stats_k<<<dim3(64,BN),256,0,stream>>>(Cc, stc3);
    // ---- final: fused addnorm stages S3 = relu(S2+norm(C3)) (ws-only inputs),
    //      plain 3x3 conv (no K), bias+relu, fp32 NCHW -> d_out ----
    pac_mfma<2,0,1,0><<<g,256,0,stream>>>(Sb, Cc,      x, Apk + 6*36864, bf,  stc3,    nullptr, (float*)d_out, nullptr, nullptr, nullptr);
}